// Round 6
// baseline (592.727 us; speedup 1.0000x reference)
//
#include <hip/hip_runtime.h>
#include <hip/hip_bf16.h>

#define NEG_SLOPE 0.2f
#define PCAP 262144  // per-bucket edge capacity (actual ~212.5K, >100 sigma margin)

typedef __attribute__((ext_vector_type(8))) short short8;
typedef __attribute__((ext_vector_type(4))) float f32x4;

__device__ __forceinline__ float lrelu(float x) { return x >= 0.f ? x : NEG_SLOPE * x; }

// pack two fp32 -> bf16x2 (RNE), low = a, high = b
__device__ __forceinline__ unsigned pack_bf2(float a, float b) {
    unsigned ua = __float_as_uint(a), ub = __float_as_uint(b);
    ua = (ua + 0x7fffu + ((ua >> 16) & 1u)) >> 16;
    ub = (ub + 0x7fffu + ((ub >> 16) & 1u)) & 0xffff0000u;
    return ua | ub;
}
__device__ __forceinline__ float2 unpack_bf2(unsigned u) {
    return make_float2(__uint_as_float(u << 16), __uint_as_float(u & 0xffff0000u));
}
__device__ __forceinline__ unsigned short bf16_of(float a) {
    unsigned ua = __float_as_uint(a);
    return (unsigned short)((ua + 0x7fffu + ((ua >> 16) & 1u)) >> 16);
}

// ---------------- Edge partition: bucket by dst range (8 buckets = XCD-pinned node ranges)
__global__ __launch_bounds__(256) void partition_kernel(const int* __restrict__ src,
                                                        const int* __restrict__ dst,
                                                        int etot, int psz, int* __restrict__ pcnt,
                                                        int* __restrict__ pdst,
                                                        int* __restrict__ psrc) {
    __shared__ int cnt[8], off[8], gofs[8];
    __shared__ int sd[256], ss[256];
    __shared__ unsigned char sb[256];
    for (int base = blockIdx.x * 256; base < etot; base += gridDim.x * 256) {
        int e = base + (int)threadIdx.x;
        bool valid = e < etot;
        int d = 0, s = 0, b = 0, my = 0;
        if (threadIdx.x < 8) cnt[threadIdx.x] = 0;
        __syncthreads();
        if (valid) {
            d = dst[e];
            s = src[e];
            b = min(d / psz, 7);
            my = atomicAdd(&cnt[b], 1);
        }
        __syncthreads();
        if (threadIdx.x == 0) {
            int r = 0;
#pragma unroll
            for (int i = 0; i < 8; ++i) { off[i] = r; r += cnt[i]; }
        }
        __syncthreads();
        if (threadIdx.x < 8) gofs[threadIdx.x] = atomicAdd(&pcnt[threadIdx.x], cnt[threadIdx.x]);
        if (valid) {
            int slot = off[b] + my;
            sd[slot] = d;
            ss[slot] = s;
            sb[slot] = (unsigned char)b;
        }
        __syncthreads();
        int total = off[7] + cnt[7];
        if ((int)threadIdx.x < total) {
            int b2 = sb[threadIdx.x];
            int pos = gofs[b2] + ((int)threadIdx.x - off[b2]);
            pdst[(size_t)b2 * PCAP + pos] = sd[threadIdx.x];
            psrc[(size_t)b2 * PCAP + pos] = ss[threadIdx.x];
        }
        __syncthreads();
    }
}

// ---------------- hist over partitioned edges (blockIdx&7 = partition -> XCD-local counts)
__global__ __launch_bounds__(256) void hist2_kernel(const int* __restrict__ pdst,
                                                    const int* __restrict__ pcnt,
                                                    int* __restrict__ counts) {
    int p = blockIdx.x & 7, stripe = blockIdx.x >> 3, NS = gridDim.x >> 3;
    int cnt = pcnt[p];
    const int* dd = pdst + (size_t)p * PCAP;
    for (int i = stripe * 256 + (int)threadIdx.x; i < cnt; i += NS * 256)
        atomicAdd(&counts[dd[i]], 1);
}

__global__ __launch_bounds__(256) void scanA_kernel(const int* __restrict__ counts,
                                                    int* __restrict__ bsums, int n) {
    __shared__ int sm[256];
    int i = blockIdx.x * 256 + threadIdx.x;
    sm[threadIdx.x] = (i < n) ? counts[i] : 0;
    __syncthreads();
    for (int off = 128; off > 0; off >>= 1) {
        if (threadIdx.x < off) sm[threadIdx.x] += sm[threadIdx.x + off];
        __syncthreads();
    }
    if (threadIdx.x == 0) bsums[blockIdx.x] = sm[0];
}

__global__ __launch_bounds__(1024) void scanB_kernel(int* __restrict__ bsums, int nb) {
    __shared__ int sm[1024];
    int t = threadIdx.x;
    int v = (t < nb) ? bsums[t] : 0;
    sm[t] = v;
    __syncthreads();
    for (int off = 1; off < 1024; off <<= 1) {
        int u = (t >= off) ? sm[t - off] : 0;
        __syncthreads();
        sm[t] += u;
        __syncthreads();
    }
    if (t < nb) bsums[t] = sm[t] - v;  // exclusive
}

__global__ __launch_bounds__(256) void scanC_kernel(const int* __restrict__ counts,
                                                    const int* __restrict__ bsums,
                                                    int* __restrict__ row_ptr,
                                                    int* __restrict__ cursor, int n, int etot) {
    __shared__ int sm[256];
    int t = threadIdx.x;
    int i = blockIdx.x * 256 + t;
    int v = (i < n) ? counts[i] : 0;
    sm[t] = v;
    __syncthreads();
    for (int off = 1; off < 256; off <<= 1) {
        int u = (t >= off) ? sm[t - off] : 0;
        __syncthreads();
        sm[t] += u;
        __syncthreads();
    }
    if (i < n) {
        int ex = bsums[blockIdx.x] + sm[t] - v;
        row_ptr[i] = ex;
        cursor[i] = ex;
    }
    if (i == 0) row_ptr[n] = etot;
}

__global__ __launch_bounds__(256) void scatter2_kernel(const int* __restrict__ pdst,
                                                       const int* __restrict__ psrc,
                                                       const int* __restrict__ pcnt,
                                                       int* __restrict__ cursor,
                                                       int* __restrict__ csr_src) {
    int p = blockIdx.x & 7, stripe = blockIdx.x >> 3, NS = gridDim.x >> 3;
    int cnt = pcnt[p];
    const int* dd = pdst + (size_t)p * PCAP;
    const int* sv = psrc + (size_t)p * PCAP;
    for (int i = stripe * 256 + (int)threadIdx.x; i < cnt; i += NS * 256) {
        int d = dd[i];
        int s = sv[i];
        int pos = atomicAdd(&cursor[d], 1);
        csr_src[pos] = s;
    }
}

// ---------------- Layer 1 GEMM via MFMA: h1(bf16) = x @ W1 ----------------
// Block 64 rows x 64 cols, K=256. Fragment layouts per verified m89/m91/m120:
// A[m=lane&15][k=quad*8+j], B^T same, C col=lane&15 row=quad*4+reg.
// LDS layout [kq][row][8] -> every b128 read is lane-contiguous, 16B aligned.
__global__ __launch_bounds__(256) void gemm1_kernel(const float* __restrict__ x,
                                                    const float* __restrict__ W1,
                                                    unsigned short* __restrict__ h1b, int n) {
    __shared__ short xb[32 * 64 * 8];  // 32 KB: [kq][m][8]
    __shared__ short wt[32 * 64 * 8];  // 32 KB: [kq][n][8]
    int tid = threadIdx.x;
    int r0 = blockIdx.x * 64;
    // stage W1 (256x64 fp32, L2-resident) -> wt, transposed to n-major fragments
    for (int t = tid; t < 16384; t += 256) {
        int k = t >> 6, nn = t & 63;  // coalesced read along nn
        wt[((size_t)(k >> 3) * 64 + nn) * 8 + (k & 7)] = (short)bf16_of(W1[t]);
    }
    // stage x tile -> xb
    for (int t = tid; t < 4096; t += 256) {
        int row = t >> 6, q = t & 63;  // float4 q covers k = 4q..4q+3
        int gr = r0 + row;
        float4 v = make_float4(0.f, 0.f, 0.f, 0.f);
        if (gr < n) v = *(const float4*)(x + (size_t)gr * 256 + 4 * q);
        uint2 u;
        u.x = pack_bf2(v.x, v.y);
        u.y = pack_bf2(v.z, v.w);
        *(uint2*)(xb + ((size_t)(q >> 1) * 64 + row) * 8 + (q & 1) * 4) = u;
    }
    __syncthreads();
    int w = tid >> 6, lane = tid & 63;
    int p = lane & 15, quad = lane >> 4;
    f32x4 z = {0.f, 0.f, 0.f, 0.f};
    f32x4 acc[4] = {z, z, z, z};
#pragma unroll
    for (int kc = 0; kc < 8; ++kc) {
        int kq = kc * 4 + quad;
        short8 a = *(const short8*)(xb + ((size_t)kq * 64 + 16 * w + p) * 8);
#pragma unroll
        for (int t = 0; t < 4; ++t) {
            short8 b = *(const short8*)(wt + ((size_t)kq * 64 + 16 * t + p) * 8);
            acc[t] = __builtin_amdgcn_mfma_f32_16x16x32_bf16(a, b, acc[t], 0, 0, 0);
        }
    }
#pragma unroll
    for (int t = 0; t < 4; ++t)
#pragma unroll
        for (int r = 0; r < 4; ++r) {
            int gr = r0 + 16 * w + quad * 4 + r;
            if (gr < n) h1b[(size_t)gr * 64 + 16 * t + p] = bf16_of(acc[t][r]);
        }
}

// alpha1 from bf16 h1: 8 rows/block (2 rows per wave, 32 lanes each)
__global__ __launch_bounds__(256) void alpha1_kernel(const unsigned short* __restrict__ h1b,
                                                     const float* __restrict__ att_s,
                                                     const float* __restrict__ att_d,
                                                     float* __restrict__ as1,
                                                     float* __restrict__ ad1, int n) {
    int wid = threadIdx.x >> 6, lane = threadIdx.x & 63;
    int p = lane & 31;
    int r = blockIdx.x * 8 + wid * 2 + (lane >> 5);
    if (r >= n) return;
    float2 sc = *(const float2*)(att_s + 2 * p);
    float2 dc = *(const float2*)(att_d + 2 * p);
    float2 h = unpack_bf2(((const unsigned*)h1b)[(size_t)r * 32 + p]);
    float ps = h.x * sc.x + h.y * sc.y;
    float pd = h.x * dc.x + h.y * dc.y;
    ps += __shfl_xor(ps, 1); pd += __shfl_xor(pd, 1);
    ps += __shfl_xor(ps, 2); pd += __shfl_xor(pd, 2);
    if ((p & 3) == 0) {
        as1[(size_t)r * 8 + (p >> 2)] = ps;
        ad1[(size_t)r * 8 + (p >> 2)] = pd;
    }
}

// ---------------- Layer 1 aggregation ----------------
__global__ __launch_bounds__(256) void agg1_kernel(const unsigned short* __restrict__ h1b,
                                                   const float* __restrict__ as1,
                                                   const float* __restrict__ ad1,
                                                   const float* __restrict__ b1,
                                                   const int* __restrict__ row_ptr,
                                                   const int* __restrict__ csr_src,
                                                   float* __restrict__ elu1, int n) {
    int lane = threadIdx.x & 63;
    int node = blockIdx.x * 4 + (threadIdx.x >> 6);
    if (node >= n) return;
    int start = row_ptr[node], end = row_ptr[node + 1];
    int slot = lane >> 3, hd = lane & 7;
    float adh = ad1[(size_t)node * 8 + hd];

    // pass 1: online softmax, (slot,head) layout, 16 edges/iter
    float m = -1e30f, den = 0.f;
    for (int base = start; base < end; base += 64) {
        int nloc = min(64, end - base);
        int eidx = base + lane;
        int sAll = (eidx < end) ? csr_src[eidx] : 0;  // coalesced
        for (int e0 = 0; e0 < nloc; e0 += 16) {
            int s0 = __shfl(sAll, e0 + slot);
            int s1 = __shfl(sAll, e0 + 8 + slot);
            float v0 = lrelu(as1[(size_t)s0 * 8 + hd] + adh);
            float v1 = lrelu(as1[(size_t)s1 * 8 + hd] + adh);
            if (e0 + slot >= nloc) v0 = -INFINITY;
            if (e0 + 8 + slot >= nloc) v1 = -INFINITY;
            float nm = fmaxf(m, fmaxf(v0, v1));
            den = den * __expf(m - nm) + __expf(v0 - nm) + __expf(v1 - nm);
            m = nm;
        }
    }
#pragma unroll
    for (int off = 8; off < 64; off <<= 1) {
        float om = __shfl_xor(m, off);
        float od = __shfl_xor(den, off);
        float nm = fmaxf(m, om);
        den = den * __expf(m - nm) + od * __expf(om - nm);
        m = nm;
    }
    float inv = 1.f / den;

    // pass 2: bf16 gather, channel-pair lanes, 2 edges per gather instr
    int q = lane >> 5, p = lane & 31, hp = p >> 2;
    const unsigned* h1u = (const unsigned*)h1b;  // row stride 32 uints (128B)
    float2 o = make_float2(0.f, 0.f);
    for (int base = start; base < end; base += 64) {
        int nloc = min(64, end - base);
        int eidx = base + lane;
        int sAll = (eidx < end) ? csr_src[eidx] : 0;
        for (int e0 = 0; e0 < nloc; e0 += 8) {
            int s = __shfl(sAll, e0 + slot);
            float v = lrelu(as1[(size_t)s * 8 + hd] + adh);
            float w = (e0 + slot < nloc) ? __expf(v - m) * inv : 0.f;
#pragma unroll
            for (int j = 0; j < 8; j += 2) {
                int sj = __shfl(s, (j + q) * 8);
                float wj = __shfl(w, (j + q) * 8 + hp);
                float2 hf = unpack_bf2(h1u[(size_t)sj * 32 + p]);
                o.x = fmaf(hf.x, wj, o.x);
                o.y = fmaf(hf.y, wj, o.y);
            }
        }
    }
    o.x += __shfl_xor(o.x, 32);
    o.y += __shfl_xor(o.y, 32);
    if (lane < 32) {
        float2 bb = *(const float2*)(b1 + 2 * p);
        float v0 = o.x + bb.x, v1 = o.y + bb.y;
        v0 = v0 > 0.f ? v0 : __expf(v0) - 1.f;
        v1 = v1 > 0.f ? v1 : __expf(v1) - 1.f;
        *(float2*)(elu1 + (size_t)node * 64 + 2 * p) = make_float2(v0, v1);
    }
}

// ---------------- Layer 2 GEMM: h2(bf16) = elu1 @ W2, fused alpha2 ----------------
__global__ __launch_bounds__(256) void gemm2_kernel(const float* __restrict__ elu1,
                                                    const float* __restrict__ W2,
                                                    const float* __restrict__ att_s,
                                                    const float* __restrict__ att_d,
                                                    unsigned short* __restrict__ h2b,
                                                    float* __restrict__ as2,
                                                    float* __restrict__ ad2, int n) {
    __shared__ float As[64][132];
    __shared__ float Bs[64][40];
    int tid = threadIdx.x;
    int r0 = blockIdx.x * 128;
    int cx = tid & 7, ry = tid >> 3;
    float sa[5], da[5];
#pragma unroll
    for (int j = 0; j < 5; ++j) {
        sa[j] = att_s[5 * cx + j];
        da[j] = att_d[5 * cx + j];
    }
    for (int t = tid; t < 640; t += 256) {
        int k = t / 10, cq = t % 10;
        *(float4*)&Bs[k][4 * cq] = *(const float4*)(W2 + (size_t)k * 40 + 4 * cq);
    }
    for (int t = tid; t < 2048; t += 256) {
        int row = t >> 4, kq = t & 15;
        int gr = r0 + row;
        float4 av = make_float4(0.f, 0.f, 0.f, 0.f);
        if (gr < n) av = *(const float4*)(elu1 + (size_t)gr * 64 + 4 * kq);
        As[4 * kq + 0][row] = av.x;
        As[4 * kq + 1][row] = av.y;
        As[4 * kq + 2][row] = av.z;
        As[4 * kq + 3][row] = av.w;
    }
    __syncthreads();
    float acc[4][5] = {{0.f}};
#pragma unroll 8
    for (int k = 0; k < 64; ++k) {
        float4 a = *(const float4*)&As[k][4 * ry];
        float ar[4] = {a.x, a.y, a.z, a.w};
        float br[5];
#pragma unroll
        for (int j = 0; j < 5; ++j) br[j] = Bs[k][5 * cx + j];
#pragma unroll
        for (int i = 0; i < 4; ++i)
#pragma unroll
            for (int j = 0; j < 5; ++j) acc[i][j] = fmaf(ar[i], br[j], acc[i][j]);
    }
#pragma unroll
    for (int i = 0; i < 4; ++i) {
        int gr = r0 + 4 * ry + i;
        float ps = 0.f, pd = 0.f;
#pragma unroll
        for (int j = 0; j < 5; ++j) {
            ps = fmaf(acc[i][j], sa[j], ps);
            pd = fmaf(acc[i][j], da[j], pd);
        }
        ps += __shfl_xor(ps, 1); pd += __shfl_xor(pd, 1);
        ps += __shfl_xor(ps, 2); pd += __shfl_xor(pd, 2);
        ps += __shfl_xor(ps, 4); pd += __shfl_xor(pd, 4);
        if (gr < n) {
#pragma unroll
            for (int j = 0; j < 5; ++j) h2b[(size_t)gr * 40 + 5 * cx + j] = bf16_of(acc[i][j]);
            if (cx == 0) {
                as2[gr] = ps;
                ad2[gr] = pd;
            }
        }
    }
}

// ---------------- Layer 2 aggregation + bias + log_softmax ----------------
__global__ __launch_bounds__(256) void agg2_kernel(const unsigned short* __restrict__ h2b,
                                                   const float* __restrict__ as2,
                                                   const float* __restrict__ ad2,
                                                   const float* __restrict__ b2,
                                                   const int* __restrict__ row_ptr,
                                                   const int* __restrict__ csr_src,
                                                   float* __restrict__ out, int n) {
    int lane = threadIdx.x & 63;
    int node = blockIdx.x * 4 + (threadIdx.x >> 6);
    if (node >= n) return;
    int start = row_ptr[node], end = row_ptr[node + 1];
    float adn = ad2[node];

    float m = -1e30f, den = 0.f;
    for (int base = start; base < end; base += 64) {
        int eidx = base + lane;
        bool valid = eidx < end;
        int s = valid ? csr_src[eidx] : 0;
        float v = lrelu(as2[s] + adn);
        if (!valid) v = -INFINITY;
        float nm = fmaxf(m, v);
        den = den * __expf(m - nm) + __expf(v - nm);
        m = nm;
    }
#pragma unroll
    for (int off = 1; off < 64; off <<= 1) {
        float om = __shfl_xor(m, off);
        float od = __shfl_xor(den, off);
        float nm = fmaxf(m, om);
        den = den * __expf(m - nm) + od * __expf(om - nm);
        m = nm;
    }
    float inv = 1.f / den;

    int q = lane >> 5, p = lane & 31;
    int pc = min(p, 19);
    const unsigned* h2u = (const unsigned*)h2b;  // row stride 20 uints (80B)
    float2 o = make_float2(0.f, 0.f);
    for (int base = start; base < end; base += 64) {
        int nloc = min(64, end - base);
        int eidx = base + lane;
        bool valid = eidx < end;
        int sAll = valid ? csr_src[eidx] : 0;
        float v = lrelu(as2[sAll] + adn);
        float w = valid ? __expf(v - m) * inv : 0.f;
        for (int g = 0; g < nloc; g += 8) {
#pragma unroll
            for (int j = 0; j < 8; j += 2) {
                int idx = g + j + q;
                int sj = __shfl(sAll, idx);
                float wj = __shfl(w, idx);
                float2 hf = unpack_bf2(h2u[(size_t)sj * 20 + pc]);
                o.x = fmaf(hf.x, wj, o.x);
                o.y = fmaf(hf.y, wj, o.y);
            }
        }
    }
    o.x += __shfl_xor(o.x, 32);
    o.y += __shfl_xor(o.y, 32);
    bool act = (lane < 32) && (p < 20);
    float v0 = -1e30f, v1 = -1e30f;
    if (act) {
        float2 bb = *(const float2*)(b2 + 2 * p);
        v0 = o.x + bb.x;
        v1 = o.y + bb.y;
    }
    float vm = fmaxf(v0, v1);
#pragma unroll
    for (int off = 1; off < 64; off <<= 1) vm = fmaxf(vm, __shfl_xor(vm, off));
    float ex = act ? (__expf(v0 - vm) + __expf(v1 - vm)) : 0.f;
#pragma unroll
    for (int off = 1; off < 64; off <<= 1) ex += __shfl_xor(ex, off);
    if (act) {
        float lg = __logf(ex);
        *(float2*)(out + (size_t)node * 40 + 2 * p) = make_float2(v0 - vm - lg, v1 - vm - lg);
    }
}

// ---------------- launch ----------------
extern "C" void kernel_launch(void* const* d_in, const int* in_sizes, int n_in,
                              void* d_out, int out_size, void* d_ws, size_t ws_size,
                              hipStream_t stream) {
    const float* x        = (const float*)d_in[0];
    const float* W1       = (const float*)d_in[1];
    const float* att_src1 = (const float*)d_in[2];
    const float* att_dst1 = (const float*)d_in[3];
    const float* b1       = (const float*)d_in[4];
    const float* W2       = (const float*)d_in[5];
    const float* att_src2 = (const float*)d_in[6];
    const float* att_dst2 = (const float*)d_in[7];
    const float* b2       = (const float*)d_in[8];
    const int*   ei       = (const int*)d_in[9];

    int n    = in_sizes[0] / 256;   // 100000
    int etot = in_sizes[9] / 2;     // 1700000
    int psz  = (n + 7) / 8;         // nodes per partition
    const int* srcp = ei;
    const int* dstp = ei + etot;

    char* ws = (char*)d_ws;
    size_t off = 0;
    unsigned short* h1b = (unsigned short*)(ws + off); off += (size_t)n * 64 * 2;
    unsigned short* h2b = (unsigned short*)(ws + off); off += (size_t)n * 40 * 2;
    float* elu1 = (float*)(ws + off); off += (size_t)n * 64 * 4;
    // pdst/psrc alias elu1 (dead before agg1 writes elu1): 2 * 8 * PCAP * 4 = 16.8 MB <= 25.6 MB
    int* pdst = (int*)elu1;
    int* psrc = pdst + (size_t)8 * PCAP;
    float* as1  = (float*)(ws + off); off += (size_t)n * 8 * 4;
    float* ad1  = (float*)(ws + off); off += (size_t)n * 8 * 4;
    float* as2  = (float*)(ws + off); off += (size_t)n * 4;
    float* ad2  = (float*)(ws + off); off += (size_t)n * 4;
    int* row_ptr = (int*)(ws + off); off += (size_t)(n + 64) * 4;
    int* counts  = (int*)(ws + off); off += (size_t)(n + 8) * 4;  // + pcnt[8]
    int* pcnt    = counts + n;
    int* cursor  = (int*)(ws + off); off += (size_t)n * 4;
    int* bsums   = (int*)(ws + off); off += (size_t)2048 * 4;
    int* csr_src = (int*)(ws + off); off += (size_t)etot * 4;
    float* outp = (float*)d_out;

    hipMemsetAsync(counts, 0, (size_t)(n + 8) * 4, stream);
    int nb256 = (n + 255) / 256;
    partition_kernel<<<2048, 256, 0, stream>>>(srcp, dstp, etot, psz, pcnt, pdst, psrc);
    hist2_kernel<<<1024, 256, 0, stream>>>(pdst, pcnt, counts);
    scanA_kernel<<<nb256, 256, 0, stream>>>(counts, bsums, n);
    scanB_kernel<<<1, 1024, 0, stream>>>(bsums, nb256);
    scanC_kernel<<<nb256, 256, 0, stream>>>(counts, bsums, row_ptr, cursor, n, etot);
    scatter2_kernel<<<1024, 256, 0, stream>>>(pdst, psrc, pcnt, cursor, csr_src);

    int nb4 = (n + 3) / 4;
    gemm1_kernel<<<(n + 63) / 64, 256, 0, stream>>>(x, W1, h1b, n);
    alpha1_kernel<<<(n + 7) / 8, 256, 0, stream>>>(h1b, att_src1, att_dst1, as1, ad1, n);
    agg1_kernel<<<nb4, 256, 0, stream>>>(h1b, as1, ad1, b1, row_ptr, csr_src, elu1, n);
    gemm2_kernel<<<(n + 127) / 128, 256, 0, stream>>>(elu1, W2, att_src2, att_dst2, h2b, as2, ad2, n);
    agg2_kernel<<<nb4, 256, 0, stream>>>(h2b, as2, ad2, b2, row_ptr, csr_src, outp, n);
}

// Round 7
// 494.271 us; speedup vs baseline: 1.1992x; 1.1992x over previous
//
#include <hip/hip_runtime.h>
#include <hip/hip_bf16.h>

#define NEG_SLOPE 0.2f

typedef __attribute__((ext_vector_type(8))) short short8;
typedef __attribute__((ext_vector_type(4))) float f32x4;

__device__ __forceinline__ float lrelu(float x) { return x >= 0.f ? x : NEG_SLOPE * x; }

// pack two fp32 -> bf16x2 (RNE), low = a, high = b
__device__ __forceinline__ unsigned pack_bf2(float a, float b) {
    unsigned ua = __float_as_uint(a), ub = __float_as_uint(b);
    ua = (ua + 0x7fffu + ((ua >> 16) & 1u)) >> 16;
    ub = (ub + 0x7fffu + ((ub >> 16) & 1u)) & 0xffff0000u;
    return ua | ub;
}
__device__ __forceinline__ float2 unpack_bf2(unsigned u) {
    return make_float2(__uint_as_float(u << 16), __uint_as_float(u & 0xffff0000u));
}
__device__ __forceinline__ unsigned short bf16_of(float a) {
    unsigned ua = __float_as_uint(a);
    return (unsigned short)((ua + 0x7fffu + ((ua >> 16) & 1u)) >> 16);
}

// ---------------- CSR build (round-5 version: XCD-partition filter) ----------------
__global__ __launch_bounds__(256) void hist_kernel(const int* __restrict__ dst,
                                                   int* __restrict__ counts, int etot, int n) {
    int part = blockIdx.x & 7;
    int stripe = blockIdx.x >> 3;
    int nstripes = gridDim.x >> 3;
    int psz = (n + 7) >> 3;
    int lo = part * psz, hi = min(n, lo + psz);
    int per = (etot + nstripes - 1) / nstripes;
    int e0 = stripe * per, e1 = min(etot, e0 + per);
    for (int e = e0 + (int)threadIdx.x; e < e1; e += 256) {
        int d = dst[e];
        if (d >= lo && d < hi) atomicAdd(&counts[d], 1);
    }
}

__global__ __launch_bounds__(256) void scanA_kernel(const int* __restrict__ counts,
                                                    int* __restrict__ bsums, int n) {
    __shared__ int sm[256];
    int i = blockIdx.x * 256 + threadIdx.x;
    sm[threadIdx.x] = (i < n) ? counts[i] : 0;
    __syncthreads();
    for (int off = 128; off > 0; off >>= 1) {
        if (threadIdx.x < off) sm[threadIdx.x] += sm[threadIdx.x + off];
        __syncthreads();
    }
    if (threadIdx.x == 0) bsums[blockIdx.x] = sm[0];
}

__global__ __launch_bounds__(1024) void scanB_kernel(int* __restrict__ bsums, int nb) {
    __shared__ int sm[1024];
    int t = threadIdx.x;
    int v = (t < nb) ? bsums[t] : 0;
    sm[t] = v;
    __syncthreads();
    for (int off = 1; off < 1024; off <<= 1) {
        int u = (t >= off) ? sm[t - off] : 0;
        __syncthreads();
        sm[t] += u;
        __syncthreads();
    }
    if (t < nb) bsums[t] = sm[t] - v;  // exclusive
}

__global__ __launch_bounds__(256) void scanC_kernel(const int* __restrict__ counts,
                                                    const int* __restrict__ bsums,
                                                    int* __restrict__ row_ptr,
                                                    int* __restrict__ cursor, int n, int etot) {
    __shared__ int sm[256];
    int t = threadIdx.x;
    int i = blockIdx.x * 256 + t;
    int v = (i < n) ? counts[i] : 0;
    sm[t] = v;
    __syncthreads();
    for (int off = 1; off < 256; off <<= 1) {
        int u = (t >= off) ? sm[t - off] : 0;
        __syncthreads();
        sm[t] += u;
        __syncthreads();
    }
    if (i < n) {
        int ex = bsums[blockIdx.x] + sm[t] - v;
        row_ptr[i] = ex;
        cursor[i] = ex;
    }
    if (i == 0) row_ptr[n] = etot;
}

__global__ __launch_bounds__(256) void scatter_kernel(const int* __restrict__ src,
                                                      const int* __restrict__ dst,
                                                      int* __restrict__ cursor,
                                                      int* __restrict__ csr_src, int etot, int n) {
    int part = blockIdx.x & 7;
    int stripe = blockIdx.x >> 3;
    int nstripes = gridDim.x >> 3;
    int psz = (n + 7) >> 3;
    int lo = part * psz, hi = min(n, lo + psz);
    int per = (etot + nstripes - 1) / nstripes;
    int e0 = stripe * per, e1 = min(etot, e0 + per);
    for (int e = e0 + (int)threadIdx.x; e < e1; e += 256) {
        int d = dst[e];
        if (d >= lo && d < hi) {
            int p = atomicAdd(&cursor[d], 1);
            csr_src[p] = src[e];
        }
    }
}

// ---------------- W1 pre-convert: fp32 [256][64] -> bf16 transposed [64][256] ----------------
__global__ __launch_bounds__(256) void w1cvt_kernel(const float* __restrict__ W1,
                                                    unsigned short* __restrict__ W1t) {
    int t = blockIdx.x * 256 + threadIdx.x;  // 16384 total
    int k = t >> 6, nn = t & 63;
    W1t[(size_t)nn * 256 + k] = bf16_of(W1[t]);
}

// ---------------- Layer 1 GEMM via MFMA, zero LDS: h1(bf16) = x @ W1 ----------------
// Block = 64 rows; wave w handles rows r0+16w..+15, all 64 cols (4 col-tiles).
// A: direct global float4 x2 -> in-register bf16. B: 16B fragments from W1t (L2-resident).
__global__ __launch_bounds__(256) void gemm1_kernel(const float* __restrict__ x,
                                                    const unsigned short* __restrict__ W1t,
                                                    unsigned short* __restrict__ h1b, int n) {
    int tid = threadIdx.x;
    int w = tid >> 6, lane = tid & 63;
    int p = lane & 15, quad = lane >> 4;
    int r0 = blockIdx.x * 64;
    int row = r0 + 16 * w + p;
    const float* xrow = x + (size_t)row * 256;
    f32x4 z = {0.f, 0.f, 0.f, 0.f};
    f32x4 acc[4] = {z, z, z, z};
#pragma unroll
    for (int kc = 0; kc < 8; ++kc) {
        int k0 = kc * 32 + quad * 8;
        float4 v0 = make_float4(0.f, 0.f, 0.f, 0.f), v1 = v0;
        if (row < n) {
            v0 = *(const float4*)(xrow + k0);
            v1 = *(const float4*)(xrow + k0 + 4);
        }
        union { uint4 u; short8 s; } a;
        a.u = make_uint4(pack_bf2(v0.x, v0.y), pack_bf2(v0.z, v0.w),
                         pack_bf2(v1.x, v1.y), pack_bf2(v1.z, v1.w));
#pragma unroll
        for (int t = 0; t < 4; ++t) {
            short8 b = *(const short8*)(W1t + (size_t)(16 * t + p) * 256 + k0);
            acc[t] = __builtin_amdgcn_mfma_f32_16x16x32_bf16(a.s, b, acc[t], 0, 0, 0);
        }
    }
#pragma unroll
    for (int t = 0; t < 4; ++t)
#pragma unroll
        for (int r = 0; r < 4; ++r) {
            int gr = r0 + 16 * w + quad * 4 + r;
            if (gr < n) h1b[(size_t)gr * 64 + 16 * t + p] = bf16_of(acc[t][r]);
        }
}

// alpha1 from bf16 h1: 8 rows/block (2 rows per wave, 32 lanes each)
__global__ __launch_bounds__(256) void alpha1_kernel(const unsigned short* __restrict__ h1b,
                                                     const float* __restrict__ att_s,
                                                     const float* __restrict__ att_d,
                                                     float* __restrict__ as1,
                                                     float* __restrict__ ad1, int n) {
    int wid = threadIdx.x >> 6, lane = threadIdx.x & 63;
    int p = lane & 31;
    int r = blockIdx.x * 8 + wid * 2 + (lane >> 5);
    if (r >= n) return;
    float2 sc = *(const float2*)(att_s + 2 * p);
    float2 dc = *(const float2*)(att_d + 2 * p);
    float2 h = unpack_bf2(((const unsigned*)h1b)[(size_t)r * 32 + p]);
    float ps = h.x * sc.x + h.y * sc.y;
    float pd = h.x * dc.x + h.y * dc.y;
    ps += __shfl_xor(ps, 1); pd += __shfl_xor(pd, 1);
    ps += __shfl_xor(ps, 2); pd += __shfl_xor(pd, 2);
    if ((p & 3) == 0) {
        as1[(size_t)r * 8 + (p >> 2)] = ps;
        ad1[(size_t)r * 8 + (p >> 2)] = pd;
    }
}

// ---------------- Layer 1 aggregation ----------------
__global__ __launch_bounds__(256) void agg1_kernel(const unsigned short* __restrict__ h1b,
                                                   const float* __restrict__ as1,
                                                   const float* __restrict__ ad1,
                                                   const float* __restrict__ b1,
                                                   const int* __restrict__ row_ptr,
                                                   const int* __restrict__ csr_src,
                                                   float* __restrict__ elu1, int n) {
    int lane = threadIdx.x & 63;
    int node = blockIdx.x * 4 + (threadIdx.x >> 6);
    if (node >= n) return;
    int start = row_ptr[node], end = row_ptr[node + 1];
    int slot = lane >> 3, hd = lane & 7;
    float adh = ad1[(size_t)node * 8 + hd];

    // pass 1: online softmax, (slot,head) layout, 16 edges/iter
    float m = -1e30f, den = 0.f;
    for (int base = start; base < end; base += 64) {
        int nloc = min(64, end - base);
        int eidx = base + lane;
        int sAll = (eidx < end) ? csr_src[eidx] : 0;  // coalesced
        for (int e0 = 0; e0 < nloc; e0 += 16) {
            int s0 = __shfl(sAll, e0 + slot);
            int s1 = __shfl(sAll, e0 + 8 + slot);
            float v0 = lrelu(as1[(size_t)s0 * 8 + hd] + adh);
            float v1 = lrelu(as1[(size_t)s1 * 8 + hd] + adh);
            if (e0 + slot >= nloc) v0 = -INFINITY;
            if (e0 + 8 + slot >= nloc) v1 = -INFINITY;
            float nm = fmaxf(m, fmaxf(v0, v1));
            den = den * __expf(m - nm) + __expf(v0 - nm) + __expf(v1 - nm);
            m = nm;
        }
    }
#pragma unroll
    for (int off = 8; off < 64; off <<= 1) {
        float om = __shfl_xor(m, off);
        float od = __shfl_xor(den, off);
        float nm = fmaxf(m, om);
        den = den * __expf(m - nm) + od * __expf(om - nm);
        m = nm;
    }
    float inv = 1.f / den;

    // pass 2: bf16 gather, channel-pair lanes, 2 edges per gather instr
    int q = lane >> 5, p = lane & 31, hp = p >> 2;
    const unsigned* h1u = (const unsigned*)h1b;  // row stride 32 uints (128B)
    float2 o = make_float2(0.f, 0.f);
    for (int base = start; base < end; base += 64) {
        int nloc = min(64, end - base);
        int eidx = base + lane;
        int sAll = (eidx < end) ? csr_src[eidx] : 0;
        for (int e0 = 0; e0 < nloc; e0 += 8) {
            int s = __shfl(sAll, e0 + slot);
            float v = lrelu(as1[(size_t)s * 8 + hd] + adh);
            float w = (e0 + slot < nloc) ? __expf(v - m) * inv : 0.f;
#pragma unroll
            for (int j = 0; j < 8; j += 2) {
                int sj = __shfl(s, (j + q) * 8);
                float wj = __shfl(w, (j + q) * 8 + hp);
                float2 hf = unpack_bf2(h1u[(size_t)sj * 32 + p]);
                o.x = fmaf(hf.x, wj, o.x);
                o.y = fmaf(hf.y, wj, o.y);
            }
        }
    }
    o.x += __shfl_xor(o.x, 32);
    o.y += __shfl_xor(o.y, 32);
    if (lane < 32) {
        float2 bb = *(const float2*)(b1 + 2 * p);
        float v0 = o.x + bb.x, v1 = o.y + bb.y;
        v0 = v0 > 0.f ? v0 : __expf(v0) - 1.f;
        v1 = v1 > 0.f ? v1 : __expf(v1) - 1.f;
        *(float2*)(elu1 + (size_t)node * 64 + 2 * p) = make_float2(v0, v1);
    }
}

// ---------------- Layer 2 GEMM: h2(bf16) = elu1 @ W2, fused alpha2 ----------------
__global__ __launch_bounds__(256) void gemm2_kernel(const float* __restrict__ elu1,
                                                    const float* __restrict__ W2,
                                                    const float* __restrict__ att_s,
                                                    const float* __restrict__ att_d,
                                                    unsigned short* __restrict__ h2b,
                                                    float* __restrict__ as2,
                                                    float* __restrict__ ad2, int n) {
    __shared__ float As[64][132];
    __shared__ float Bs[64][40];
    int tid = threadIdx.x;
    int r0 = blockIdx.x * 128;
    int cx = tid & 7, ry = tid >> 3;
    float sa[5], da[5];
#pragma unroll
    for (int j = 0; j < 5; ++j) {
        sa[j] = att_s[5 * cx + j];
        da[j] = att_d[5 * cx + j];
    }
    for (int t = tid; t < 640; t += 256) {
        int k = t / 10, cq = t % 10;
        *(float4*)&Bs[k][4 * cq] = *(const float4*)(W2 + (size_t)k * 40 + 4 * cq);
    }
    for (int t = tid; t < 2048; t += 256) {
        int row = t >> 4, kq = t & 15;
        int gr = r0 + row;
        float4 av = make_float4(0.f, 0.f, 0.f, 0.f);
        if (gr < n) av = *(const float4*)(elu1 + (size_t)gr * 64 + 4 * kq);
        As[4 * kq + 0][row] = av.x;
        As[4 * kq + 1][row] = av.y;
        As[4 * kq + 2][row] = av.z;
        As[4 * kq + 3][row] = av.w;
    }
    __syncthreads();
    float acc[4][5] = {{0.f}};
#pragma unroll 8
    for (int k = 0; k < 64; ++k) {
        float4 a = *(const float4*)&As[k][4 * ry];
        float ar[4] = {a.x, a.y, a.z, a.w};
        float br[5];
#pragma unroll
        for (int j = 0; j < 5; ++j) br[j] = Bs[k][5 * cx + j];
#pragma unroll
        for (int i = 0; i < 4; ++i)
#pragma unroll
            for (int j = 0; j < 5; ++j) acc[i][j] = fmaf(ar[i], br[j], acc[i][j]);
    }
#pragma unroll
    for (int i = 0; i < 4; ++i) {
        int gr = r0 + 4 * ry + i;
        float ps = 0.f, pd = 0.f;
#pragma unroll
        for (int j = 0; j < 5; ++j) {
            ps = fmaf(acc[i][j], sa[j], ps);
            pd = fmaf(acc[i][j], da[j], pd);
        }
        ps += __shfl_xor(ps, 1); pd += __shfl_xor(pd, 1);
        ps += __shfl_xor(ps, 2); pd += __shfl_xor(pd, 2);
        ps += __shfl_xor(ps, 4); pd += __shfl_xor(pd, 4);
        if (gr < n) {
#pragma unroll
            for (int j = 0; j < 5; ++j) h2b[(size_t)gr * 40 + 5 * cx + j] = bf16_of(acc[i][j]);
            if (cx == 0) {
                as2[gr] = ps;
                ad2[gr] = pd;
            }
        }
    }
}

// ---------------- Layer 2 aggregation + bias + log_softmax ----------------
__global__ __launch_bounds__(256) void agg2_kernel(const unsigned short* __restrict__ h2b,
                                                   const float* __restrict__ as2,
                                                   const float* __restrict__ ad2,
                                                   const float* __restrict__ b2,
                                                   const int* __restrict__ row_ptr,
                                                   const int* __restrict__ csr_src,
                                                   float* __restrict__ out, int n) {
    int lane = threadIdx.x & 63;
    int node = blockIdx.x * 4 + (threadIdx.x >> 6);
    if (node >= n) return;
    int start = row_ptr[node], end = row_ptr[node + 1];
    float adn = ad2[node];

    float m = -1e30f, den = 0.f;
    for (int base = start; base < end; base += 64) {
        int eidx = base + lane;
        bool valid = eidx < end;
        int s = valid ? csr_src[eidx] : 0;
        float v = lrelu(as2[s] + adn);
        if (!valid) v = -INFINITY;
        float nm = fmaxf(m, v);
        den = den * __expf(m - nm) + __expf(v - nm);
        m = nm;
    }
#pragma unroll
    for (int off = 1; off < 64; off <<= 1) {
        float om = __shfl_xor(m, off);
        float od = __shfl_xor(den, off);
        float nm = fmaxf(m, om);
        den = den * __expf(m - nm) + od * __expf(om - nm);
        m = nm;
    }
    float inv = 1.f / den;

    int q = lane >> 5, p = lane & 31;
    int pc = min(p, 19);
    const unsigned* h2u = (const unsigned*)h2b;  // row stride 20 uints (80B)
    float2 o = make_float2(0.f, 0.f);
    for (int base = start; base < end; base += 64) {
        int nloc = min(64, end - base);
        int eidx = base + lane;
        bool valid = eidx < end;
        int sAll = valid ? csr_src[eidx] : 0;
        float v = lrelu(as2[sAll] + adn);
        float w = valid ? __expf(v - m) * inv : 0.f;
        for (int g = 0; g < nloc; g += 8) {
#pragma unroll
            for (int j = 0; j < 8; j += 2) {
                int idx = g + j + q;
                int sj = __shfl(sAll, idx);
                float wj = __shfl(w, idx);
                float2 hf = unpack_bf2(h2u[(size_t)sj * 20 + pc]);
                o.x = fmaf(hf.x, wj, o.x);
                o.y = fmaf(hf.y, wj, o.y);
            }
        }
    }
    o.x += __shfl_xor(o.x, 32);
    o.y += __shfl_xor(o.y, 32);
    bool act = (lane < 32) && (p < 20);
    float v0 = -1e30f, v1 = -1e30f;
    if (act) {
        float2 bb = *(const float2*)(b2 + 2 * p);
        v0 = o.x + bb.x;
        v1 = o.y + bb.y;
    }
    float vm = fmaxf(v0, v1);
#pragma unroll
    for (int off = 1; off < 64; off <<= 1) vm = fmaxf(vm, __shfl_xor(vm, off));
    float ex = act ? (__expf(v0 - vm) + __expf(v1 - vm)) : 0.f;
#pragma unroll
    for (int off = 1; off < 64; off <<= 1) ex += __shfl_xor(ex, off);
    if (act) {
        float lg = __logf(ex);
        *(float2*)(out + (size_t)node * 40 + 2 * p) = make_float2(v0 - vm - lg, v1 - vm - lg);
    }
}

// ---------------- launch ----------------
extern "C" void kernel_launch(void* const* d_in, const int* in_sizes, int n_in,
                              void* d_out, int out_size, void* d_ws, size_t ws_size,
                              hipStream_t stream) {
    const float* x        = (const float*)d_in[0];
    const float* W1       = (const float*)d_in[1];
    const float* att_src1 = (const float*)d_in[2];
    const float* att_dst1 = (const float*)d_in[3];
    const float* b1       = (const float*)d_in[4];
    const float* W2       = (const float*)d_in[5];
    const float* att_src2 = (const float*)d_in[6];
    const float* att_dst2 = (const float*)d_in[7];
    const float* b2       = (const float*)d_in[8];
    const int*   ei       = (const int*)d_in[9];

    int n    = in_sizes[0] / 256;   // 100000
    int etot = in_sizes[9] / 2;     // 1700000
    const int* srcp = ei;
    const int* dstp = ei + etot;

    char* ws = (char*)d_ws;
    size_t off = 0;
    unsigned short* h1b = (unsigned short*)(ws + off); off += (size_t)n * 64 * 2;
    unsigned short* h2b = (unsigned short*)(ws + off); off += (size_t)n * 40 * 2;
    unsigned short* W1t = (unsigned short*)(ws + off); off += (size_t)64 * 256 * 2;
    float* elu1 = (float*)(ws + off); off += (size_t)n * 64 * 4;
    float* as1  = (float*)(ws + off); off += (size_t)n * 8 * 4;
    float* ad1  = (float*)(ws + off); off += (size_t)n * 8 * 4;
    float* as2  = (float*)(ws + off); off += (size_t)n * 4;
    float* ad2  = (float*)(ws + off); off += (size_t)n * 4;
    int* row_ptr = (int*)(ws + off); off += (size_t)(n + 64) * 4;
    int* counts  = (int*)(ws + off); off += (size_t)n * 4;
    int* cursor  = (int*)(ws + off); off += (size_t)n * 4;
    int* bsums   = (int*)(ws + off); off += (size_t)2048 * 4;
    int* csr_src = (int*)(ws + off); off += (size_t)etot * 4;
    float* outp = (float*)d_out;

    hipMemsetAsync(counts, 0, (size_t)n * 4, stream);
    int nb256 = (n + 255) / 256;
    hist_kernel<<<2048, 256, 0, stream>>>(dstp, counts, etot, n);
    scanA_kernel<<<nb256, 256, 0, stream>>>(counts, bsums, n);
    scanB_kernel<<<1, 1024, 0, stream>>>(bsums, nb256);
    scanC_kernel<<<nb256, 256, 0, stream>>>(counts, bsums, row_ptr, cursor, n, etot);
    scatter_kernel<<<2048, 256, 0, stream>>>(srcp, dstp, cursor, csr_src, etot, n);

    int nb4 = (n + 3) / 4;
    w1cvt_kernel<<<64, 256, 0, stream>>>(W1, W1t);
    gemm1_kernel<<<(n + 63) / 64, 256, 0, stream>>>(x, W1t, h1b, n);
    alpha1_kernel<<<(n + 7) / 8, 256, 0, stream>>>(h1b, att_src1, att_dst1, as1, ad1, n);
    agg1_kernel<<<nb4, 256, 0, stream>>>(h1b, as1, ad1, b1, row_ptr, csr_src, elu1, n);
    gemm2_kernel<<<(n + 127) / 128, 256, 0, stream>>>(elu1, W2, att_src2, att_dst2, h2b, as2, ad2, n);
    agg2_kernel<<<nb4, 256, 0, stream>>>(h2b, as2, ad2, b2, row_ptr, csr_src, outp, n);
}